// Round 1
// baseline (90.321 us; speedup 1.0000x reference)
//
#include <hip/hip_runtime.h>

#define IN_DIM     4288   // 64*64 + 8*24
#define LOGITS_DIM 4096
#define PP_DIM     192
#define OUT_DIM    1858
#define MAXNZ      8

// --- kernel 1: zero the per-column nonzero counters (ws is poisoned 0xAA) ---
__global__ void zero_cnt_kernel(int* __restrict__ cnt) {
    int j = blockIdx.x * blockDim.x + threadIdx.x;
    if (j < OUT_DIM) cnt[j] = 0;
}

// --- kernel 2: build sparse (idx,val) per output column from fc1 ---
// General: handles any fc1 with <= MAXNZ nonzeros per column (actual: exactly 1).
__global__ void build_csc_kernel(const float* __restrict__ fc1,
                                 int* __restrict__ cnt,
                                 int* __restrict__ idx,
                                 float* __restrict__ val) {
    const long total4 = (long)IN_DIM * OUT_DIM / 4;   // 7,967,104 / 4
    const long stride = (long)gridDim.x * blockDim.x;
    for (long t = blockIdx.x * (long)blockDim.x + threadIdx.x; t < total4; t += stride) {
        float4 v = ((const float4*)fc1)[t];
        float vv[4] = {v.x, v.y, v.z, v.w};
        #pragma unroll
        for (int c = 0; c < 4; ++c) {
            if (vv[c] != 0.0f) {
                long e = t * 4 + c;
                int j = (int)(e % OUT_DIM);   // column (fc1 is [IN_DIM][OUT_DIM] row-major)
                int i = (int)(e / OUT_DIM);   // row = input index
                int slot = atomicAdd(&cnt[j], 1);
                if (slot < MAXNZ) {
                    idx[j * MAXNZ + slot] = i;
                    val[j * MAXNZ + slot] = vv[c];
                }
            }
        }
    }
}

// --- kernel 3: per-batch-row gather through LDS ---
__global__ __launch_bounds__(256) void gather_kernel(
        const float* __restrict__ logits,
        const float* __restrict__ pp,
        const int*   __restrict__ cnt,
        const int*   __restrict__ idx,
        const float* __restrict__ val,
        float*       __restrict__ out) {
    __shared__ float row[IN_DIM];
    const int b = blockIdx.x;

    // stage the full 4288-float input row, coalesced float4
    const float4* lg4 = (const float4*)(logits + (size_t)b * LOGITS_DIM);
    float4* row4 = (float4*)row;
    for (int t = threadIdx.x; t < LOGITS_DIM / 4; t += 256)
        row4[t] = lg4[t];
    const float4* pp4 = (const float4*)(pp + (size_t)b * PP_DIM);
    float4* rowp4 = (float4*)(row + LOGITS_DIM);
    for (int t = threadIdx.x; t < PP_DIM / 4; t += 256)
        rowp4[t] = pp4[t];
    __syncthreads();

    // each thread produces a strided set of output columns; writes coalesced
    for (int j = threadIdx.x; j < OUT_DIM; j += 256) {
        int c = cnt[j];
        c = c > MAXNZ ? MAXNZ : c;
        float acc = 0.0f;
        for (int k = 0; k < c; ++k)
            acc += val[j * MAXNZ + k] * row[idx[j * MAXNZ + k]];
        out[(size_t)b * OUT_DIM + j] = acc;
    }
}

extern "C" void kernel_launch(void* const* d_in, const int* in_sizes, int n_in,
                              void* d_out, int out_size, void* d_ws, size_t ws_size,
                              hipStream_t stream) {
    const float* logits = (const float*)d_in[0];   // [B, 64, 64] f32
    const float* pp     = (const float*)d_in[1];   // [B, 8, 24] f32
    const float* fc1    = (const float*)d_in[2];   // [4288, 1858] f32
    float* out = (float*)d_out;                    // [B, 1858] f32

    const int B = in_sizes[0] / LOGITS_DIM;        // 8192

    // workspace layout: cnt[OUT_DIM] | idx[OUT_DIM*MAXNZ] | val[OUT_DIM*MAXNZ]
    int*   cnt = (int*)d_ws;
    int*   idx = cnt + OUT_DIM;
    float* val = (float*)(idx + OUT_DIM * MAXNZ);

    zero_cnt_kernel<<<(OUT_DIM + 255) / 256, 256, 0, stream>>>(cnt);
    build_csc_kernel<<<1024, 256, 0, stream>>>(fc1, cnt, idx, val);
    gather_kernel<<<B, 256, 0, stream>>>(logits, pp, cnt, idx, val, out);
}

// Round 2
// 46.401 us; speedup vs baseline: 1.9465x; 1.9465x over previous
//
#include <hip/hip_runtime.h>

#define IN_DIM     4288   // 64*64 + 8*24
#define LOGITS_DIM 4096
#define PP_DIM     192
#define OUT_DIM    1858
#define PADDED_OUT 2048   // OUT_DIM padded so u<8 register loads need no guard
#define MAXNZ      8      // general-correctness bound on nonzeros per column
#define OVF        (MAXNZ - 1)

// workspace word layout: cnt[OUT_DIM] | flag[1] | idx1[PADDED_OUT] | val1[PADDED_OUT]
//                        | idxo[OUT_DIM*OVF] | valo[OUT_DIM*OVF]
#define WS_WORDS (OUT_DIM + 1 + 2 * PADDED_OUT + 2 * OUT_DIM * OVF)

// --- kernel 1: zero the whole sparse-rep region (ws is poisoned 0xAA) ---
__global__ void zero_ws_kernel(int* __restrict__ w) {
    for (int t = blockIdx.x * blockDim.x + threadIdx.x; t < WS_WORDS;
         t += gridDim.x * blockDim.x)
        w[t] = 0;
}

// --- kernel 2: build zero-padded sparse rep of fc1 ---
// Slot 0 goes to packed idx1/val1; slots 1..MAXNZ-1 go to overflow arrays and
// raise `flag` (uniform slow path). Actual data: exactly 1 nz/col -> flag stays 0.
__global__ void build_csc_kernel(const float* __restrict__ fc1,
                                 int* __restrict__ cnt,
                                 int* __restrict__ flag,
                                 int* __restrict__ idx1,
                                 float* __restrict__ val1,
                                 int* __restrict__ idxo,
                                 float* __restrict__ valo) {
    const long total4 = (long)IN_DIM * OUT_DIM / 4;
    const long stride = (long)gridDim.x * blockDim.x;
    for (long t = blockIdx.x * (long)blockDim.x + threadIdx.x; t < total4; t += stride) {
        float4 v = ((const float4*)fc1)[t];
        float vv[4] = {v.x, v.y, v.z, v.w};
        #pragma unroll
        for (int c = 0; c < 4; ++c) {
            if (vv[c] != 0.0f) {
                long e = t * 4 + c;
                int j = (int)(e % OUT_DIM);   // column (fc1 is [IN_DIM][OUT_DIM] row-major)
                int i = (int)(e / OUT_DIM);   // row = input index
                int slot = atomicAdd(&cnt[j], 1);
                if (slot == 0) {
                    idx1[j] = i;
                    val1[j] = vv[c];
                } else if (slot < MAXNZ) {
                    idxo[j * OVF + slot - 1] = i;
                    valo[j * OVF + slot - 1] = vv[c];
                    *flag = 1;
                }
            }
        }
    }
}

// --- kernel 3: per-batch-row gather through LDS, fully unrolled fast path ---
__global__ __launch_bounds__(256) void gather_kernel(
        const float* __restrict__ logits,
        const float* __restrict__ pp,
        const int*   __restrict__ flag,
        const int*   __restrict__ idx1,
        const float* __restrict__ val1,
        const int*   __restrict__ idxo,
        const float* __restrict__ valo,
        float*       __restrict__ out) {
    __shared__ float row[IN_DIM];
    const int b   = blockIdx.x;
    const int tid = threadIdx.x;

    // stage the 4288-float input row: 4 float4/thread (logits) + guarded pp tail
    const float4* lg4 = (const float4*)(logits + (size_t)b * LOGITS_DIM);
    float4* row4 = (float4*)row;
    #pragma unroll
    for (int u = 0; u < 4; ++u)
        row4[tid + u * 256] = lg4[tid + u * 256];
    if (tid < PP_DIM / 4)
        ((float4*)(row + LOGITS_DIM))[tid] =
            ((const float4*)(pp + (size_t)b * PP_DIM))[tid];

    // hoist this thread's 8 (idx,val) pairs into registers — overlaps staging,
    // all loads independent; arrays padded to PADDED_OUT so no guard needed
    int   ridx[8];
    float rval[8];
    #pragma unroll
    for (int u = 0; u < 8; ++u) {
        int j = tid + u * 256;
        ridx[u] = idx1[j];
        rval[u] = val1[j];
    }
    const int of = *flag;   // wave-uniform

    __syncthreads();

    float* orow = out + (size_t)b * OUT_DIM;
    if (of == 0) {
        // fast path: 8 independent LDS gathers + fmuls, no runtime loop
        #pragma unroll
        for (int u = 0; u < 8; ++u) {
            int j = tid + u * 256;
            if (j < OUT_DIM) orow[j] = rval[u] * row[ridx[u]];
        }
    } else {
        // general path: compile-time MAXNZ unroll over zero-padded overflow slots
        #pragma unroll
        for (int u = 0; u < 8; ++u) {
            int j = tid + u * 256;
            if (j < OUT_DIM) {
                float acc = rval[u] * row[ridx[u]];
                #pragma unroll
                for (int k = 0; k < OVF; ++k)
                    acc += valo[j * OVF + k] * row[idxo[j * OVF + k]];
                orow[j] = acc;
            }
        }
    }
}

extern "C" void kernel_launch(void* const* d_in, const int* in_sizes, int n_in,
                              void* d_out, int out_size, void* d_ws, size_t ws_size,
                              hipStream_t stream) {
    const float* logits = (const float*)d_in[0];   // [B, 64, 64] f32
    const float* pp     = (const float*)d_in[1];   // [B, 8, 24] f32
    const float* fc1    = (const float*)d_in[2];   // [4288, 1858] f32
    float* out = (float*)d_out;                    // [B, 1858] f32

    const int B = in_sizes[0] / LOGITS_DIM;        // 8192

    int*   w    = (int*)d_ws;
    int*   cnt  = w;
    int*   flag = cnt + OUT_DIM;
    int*   idx1 = flag + 1;
    float* val1 = (float*)(idx1 + PADDED_OUT);
    int*   idxo = (int*)(val1 + PADDED_OUT);
    float* valo = (float*)(idxo + OUT_DIM * OVF);

    zero_ws_kernel<<<128, 256, 0, stream>>>(w);
    build_csc_kernel<<<1024, 256, 0, stream>>>(fc1, cnt, flag, idx1, val1, idxo, valo);
    gather_kernel<<<B, 256, 0, stream>>>(logits, pp, flag, idx1, val1, idxo, valo, out);
}